// Round 14
// baseline (135.906 us; speedup 1.0000x reference)
//
#include <hip/hip_runtime.h>
#include <hip/hip_bf16.h>
#include <math.h>

#define E_EDGES 1000000
#define N_NODES 50000
#define N_C     64
#define N_REL   8
#define CHB     2048        // edges per block (best measured: R3/R10)
#define CAP     384         // per-rel LDS capacity (mean 256, sigma 15 -> 8.5 sigma)
#define NBLK    489         // ceil(1e6 / 2048)
#define BT      512         // 8 waves per block
#define SENT    0xFFFFFFFFu

typedef __attribute__((ext_vector_type(4))) float floatx4;
typedef __attribute__((ext_vector_type(2))) float floatx2;

// pack 4 fp32 -> 4 fp8 e4m3 (RNE); byte j = element j
static __device__ __forceinline__ unsigned pk4_fp8(float a, float b, float c, float d) {
    unsigned w = 0;
    w = __builtin_amdgcn_cvt_pk_fp8_f32(a, b, w, false);
    w = __builtin_amdgcn_cvt_pk_fp8_f32(c, d, w, true);
    return w;
}

static __device__ __forceinline__ long long pack64(unsigned lo, unsigned hi) {
    uint2 u; u.x = lo; u.y = hi;
    return __builtin_bit_cast(long long, u);
}

// kappa slot permutation (verified R11/R12): Wp8 byte (q*16 + c*8 + j) of row
// holds fp8(W[row][(2c+(j>>2))*16 + 4q + (j&3)]); AS8 row byte q*16+u holds
// elem (u>>2)*16 + 4q + (u&3). One b128 per lane serves both the MFMA B-op
// and the src dot.
__global__ __launch_bounds__(256) void prep_kernel(
    const float* __restrict__ assign,
    const float* __restrict__ icl,
    const float* __restrict__ la,
    unsigned char* __restrict__ Wp8,
    unsigned char* __restrict__ AS8,
    float* __restrict__ out)
{
    int tid = blockIdx.x * blockDim.x + threadIdx.x;
    int nth = gridDim.x * blockDim.x;
    if (tid == 0) out[0] = 0.0f;

    // Wp8: one thread per output dword (512 rows x 16 dwords)
    for (int idx = tid; idx < N_REL * N_C * 16; idx += nth) {
        int row = idx >> 4, dq = idx & 15;
        int q = dq >> 2, c = (dq >> 1) & 1, jh = dq & 1;
        int k0 = (2 * c + jh) * 16 + 4 * q;   // bytes b=0..3 -> k = k0 + b
        float wv[4];
        #pragma unroll
        for (int b = 0; b < 4; ++b) {
            int srci = (row << 6) + k0 + b;
            float w = 1.0f / (1.0f + __expf(-icl[srci]));
            float g = 1.0f / (1.0f + __expf(-la[srci])) * 1.2f - 0.1f;
            g = fminf(fmaxf(g, 0.0f), 1.0f);
            wv[b] = w * g;
        }
        ((unsigned*)Wp8)[idx] = pk4_fp8(wv[0], wv[1], wv[2], wv[3]);
    }

    // AS8: one thread per node row; dword[q*4 + mt] = elems [16mt+4q, +4)
    for (int n = tid; n < N_NODES; n += nth) {
        const float4* a4 = (const float4*)(assign + (size_t)n * N_C);
        unsigned w[16];
        #pragma unroll
        for (int i = 0; i < 16; ++i) {
            float4 v = a4[i];
            w[i] = pk4_fp8(v.x, v.y, v.z, v.w);   // w[i] = elems 4i..4i+3
        }
        uint4* as = (uint4*)(AS8 + (size_t)n * N_C);
        #pragma unroll
        for (int q = 0; q < 4; ++q) {
            uint4 o;
            o.x = w[0 * 4 + q];
            o.y = w[1 * 4 + q];
            o.z = w[2 * 4 + q];
            o.w = w[3 * 4 + q];
            as[q] = o;
        }
    }
}

// R14: R10's measured structure (48.0us, spill-free) with the LAST
// conditional vmem load removed from the hot loop. R10 still reloaded wfm
// from global on relation change (scalar branch) -> compiler must drain
// vmcnt before every wfm-consuming MFMA -> S/D prefetch collapsed (VGPR=36).
// Fix: W+bias staged once in LDS, QUAD-MAJOR layout Wl[quad*512+row] so
// consecutive n16 lanes read consecutive 16B chunks (conflict-free b128;
// R8's row-major-x4 layout was a 4-way conflict, 2.79M), read
// unconditionally per item (lgkmcnt domain). Loop is a copy-free ping-pong:
// two disjoint stage sets, manual unroll x2, fetch distance 2 items
// (~500cy) -> no rotation copies, no conditional vmem; both known
// pipeline-collapse mechanisms removed.
__global__ __launch_bounds__(BT, 5) void edge_kernel(
    const unsigned char* __restrict__ AS8,
    const unsigned char* __restrict__ Wp8,
    const float* __restrict__ absent_bias,
    const int* __restrict__ ei, const int* __restrict__ et,
    const int* __restrict__ nei, const int* __restrict__ net,
    float* __restrict__ out)
{
    __shared__ uint4 Wl[N_REL * N_C * 4];    // 32768 B, quad-major
    __shared__ unsigned list[N_REL * CAP];   // 12288 B
    __shared__ float bias_l[N_REL];
    __shared__ unsigned cnt[N_REL];
    __shared__ float red[8];
    if (threadIdx.x < N_REL) {
        cnt[threadIdx.x] = 0u;
        bias_l[threadIdx.x] = absent_bias[threadIdx.x];
    }

    // stage W: global dword-quad e -> Wl[quad*512 + row], row=e>>2, quad=e&3
    {
        const uint4* Wg = (const uint4*)Wp8;
        #pragma unroll
        for (int k = 0; k < 4; ++k) {
            int e = threadIdx.x + k * BT;
            Wl[(e & 3) * 512 + (e >> 2)] = Wg[e];
        }
    }

    int blk = blockIdx.x;
    bool isneg = blk >= NBLK;
    int lb = isneg ? blk - NBLK : blk;
    const int* Es = isneg ? nei : ei;
    const int* Et = isneg ? net : et;
    float sign = isneg ? 1.0f : -1.0f;
    int base = lb * CHB;
    int elim = min(base + CHB, E_EDGES);

    __syncthreads();   // cnt=0 visible before atomics

    // binning: batch all nt-loads up front (4-deep MLP), then atomics
    {
        int e0 = base + threadIdx.x;
        int sv[4], dv[4], rv[4];
        bool mv[4];
        #pragma unroll
        for (int k = 0; k < 4; ++k) {
            int e = e0 + k * BT;
            mv[k] = e < elim;
            int ec = mv[k] ? e : base;
            sv[k] = __builtin_nontemporal_load(&Es[ec]);
            dv[k] = __builtin_nontemporal_load(&Es[E_EDGES + ec]);
            rv[k] = __builtin_nontemporal_load(&Et[ec]);
        }
        #pragma unroll
        for (int k = 0; k < 4; ++k) {
            if (mv[k]) {
                unsigned rank = atomicAdd(&cnt[rv[k]], 1u);
                if (rank < CAP)
                    list[rv[k] * CAP + rank] = (unsigned)sv[k] | ((unsigned)dv[k] << 16);
            }
        }
    }
    __syncthreads();

    // sentinel-pad each relation's list up to a multiple of 16 entries
    if (threadIdx.x < N_REL * 16) {
        int r = threadIdx.x >> 4;
        int i = threadIdx.x & 15;
        int n = min((int)cnt[r], CAP);
        int padded = ((n + 15) >> 4) << 4;
        int slot = n + i;
        if (slot < padded) list[r * CAP + slot] = SENT;
    }
    __syncthreads();

    int lane = threadIdx.x & 63;
    int wid  = __builtin_amdgcn_readfirstlane(threadIdx.x >> 6);   // 0..7
    int n16  = lane & 15;
    int quad = lane >> 4;
    float loss = 0.0f;

    // group-offset table, scalar-resident (readfirstlane -> SGPR)
    int G0 = __builtin_amdgcn_readfirstlane((min((int)cnt[0], CAP) + 15) >> 4);
    int G1 = __builtin_amdgcn_readfirstlane((min((int)cnt[1], CAP) + 15) >> 4);
    int G2 = __builtin_amdgcn_readfirstlane((min((int)cnt[2], CAP) + 15) >> 4);
    int G3 = __builtin_amdgcn_readfirstlane((min((int)cnt[3], CAP) + 15) >> 4);
    int G4 = __builtin_amdgcn_readfirstlane((min((int)cnt[4], CAP) + 15) >> 4);
    int G5 = __builtin_amdgcn_readfirstlane((min((int)cnt[5], CAP) + 15) >> 4);
    int G6 = __builtin_amdgcn_readfirstlane((min((int)cnt[6], CAP) + 15) >> 4);
    int G7 = __builtin_amdgcn_readfirstlane((min((int)cnt[7], CAP) + 15) >> 4);
    int go1 = G0;
    int go2 = go1 + G1;
    int go3 = go2 + G2;
    int go4 = go3 + G3;
    int go5 = go4 + G4;
    int go6 = go5 + G5;
    int go7 = go6 + G6;
    int tg  = go7 + G7;
    int tgm1 = tg - 1;

    #define LOCATE(ITEM, R, GOF)                                   \
        do {                                                       \
            R = 0; GOF = 0;                                        \
            if ((ITEM) >= go1) { R = 1; GOF = go1; }               \
            if ((ITEM) >= go2) { R = 2; GOF = go2; }               \
            if ((ITEM) >= go3) { R = 3; GOF = go3; }               \
            if ((ITEM) >= go4) { R = 4; GOF = go4; }               \
            if ((ITEM) >= go5) { R = 5; GOF = go5; }               \
            if ((ITEM) >= go6) { R = 6; GOF = go6; }               \
            if ((ITEM) >= go7) { R = 7; GOF = go7; }               \
        } while (0)

    // branchless per-item issue: clamped scalar LOCATE + LDS rec read +
    // S/D gathers (only vmem in the loop) + unconditional W/bias LDS reads
    #define ISSUE(VIT, RECV, SREG, DREG, WF0, WF1, WF2, WF3, BI)             \
        do {                                                                 \
            int vc_ = (VIT) < tgm1 ? (VIT) : tgm1;                           \
            int r_, gof_;                                                    \
            LOCATE(vc_, r_, gof_);                                           \
            unsigned recr_ = list[r_ * CAP + (vc_ - gof_) * 16 + n16];       \
            RECV = (VIT) < end ? recr_ : SENT;                               \
            unsigned sm_ = RECV != SENT ? (RECV & 0xFFFFu) : 0u;             \
            unsigned dm_ = RECV != SENT ? (RECV >> 16) : 0u;                 \
            SREG = *(const uint4*)(AS8 + ((size_t)sm_ << 6) + quad * 16);    \
            DREG = *(const uint4*)(AS8 + ((size_t)dm_ << 6) + quad * 16);    \
            int wb_ = quad * 512 + r_ * 64 + n16;                            \
            WF0 = Wl[wb_];                                                   \
            WF1 = Wl[wb_ + 16];                                              \
            WF2 = Wl[wb_ + 32];                                              \
            WF3 = Wl[wb_ + 48];                                              \
            BI = bias_l[r_];                                                 \
        } while (0)

    // compute one item from its stage regs; branchless loss accumulate
    #define COMPUTE(RECV, SS, DD, WF0, WF1, WF2, WF3, BI)                    \
        do {                                                                 \
            long long bD0 = pack64((DD).x, (DD).y);                          \
            long long bD1 = pack64((DD).z, (DD).w);                          \
            unsigned sw0 = (SS).x, sw1 = (SS).y, sw2 = (SS).z, sw3 = (SS).w; \
            float d0 = 0.0f, d1 = 0.0f;                                      \
            {                                                                \
                floatx4 p0 = zero4, p1 = zero4;                              \
                p0 = __builtin_amdgcn_mfma_f32_16x16x32_fp8_fp8(             \
                        pack64((WF0).x, (WF0).y), bD0, p0, 0, 0, 0);         \
                p1 = __builtin_amdgcn_mfma_f32_16x16x32_fp8_fp8(             \
                        pack64((WF1).x, (WF1).y), bD0, p1, 0, 0, 0);         \
                p0 = __builtin_amdgcn_mfma_f32_16x16x32_fp8_fp8(             \
                        pack64((WF0).z, (WF0).w), bD1, p0, 0, 0, 0);         \
                p1 = __builtin_amdgcn_mfma_f32_16x16x32_fp8_fp8(             \
                        pack64((WF1).z, (WF1).w), bD1, p1, 0, 0, 0);         \
                floatx2 lo0 = __builtin_amdgcn_cvt_pk_f32_fp8((int)sw0, false);\
                floatx2 hi0 = __builtin_amdgcn_cvt_pk_f32_fp8((int)sw0, true);\
                floatx2 lo1 = __builtin_amdgcn_cvt_pk_f32_fp8((int)sw1, false);\
                floatx2 hi1 = __builtin_amdgcn_cvt_pk_f32_fp8((int)sw1, true);\
                d0 = fmaf(lo0.x, p0[0], d0); d1 = fmaf(lo1.x, p1[0], d1);    \
                d0 = fmaf(lo0.y, p0[1], d0); d1 = fmaf(lo1.y, p1[1], d1);    \
                d0 = fmaf(hi0.x, p0[2], d0); d1 = fmaf(hi1.x, p1[2], d1);    \
                d0 = fmaf(hi0.y, p0[3], d0); d1 = fmaf(hi1.y, p1[3], d1);    \
            }                                                                \
            {                                                                \
                floatx4 p0 = zero4, p1 = zero4;                              \
                p0 = __builtin_amdgcn_mfma_f32_16x16x32_fp8_fp8(             \
                        pack64((WF2).x, (WF2).y), bD0, p0, 0, 0, 0);         \
                p1 = __builtin_amdgcn_mfma_f32_16x16x32_fp8_fp8(             \
                        pack64((WF3).x, (WF3).y), bD0, p1, 0, 0, 0);         \
                p0 = __builtin_amdgcn_mfma_f32_16x16x32_fp8_fp8(             \
                        pack64((WF2).z, (WF2).w), bD1, p0, 0, 0, 0);         \
                p1 = __builtin_amdgcn_mfma_f32_16x16x32_fp8_fp8(             \
                        pack64((WF3).z, (WF3).w), bD1, p1, 0, 0, 0);         \
                floatx2 lo0 = __builtin_amdgcn_cvt_pk_f32_fp8((int)sw2, false);\
                floatx2 hi0 = __builtin_amdgcn_cvt_pk_f32_fp8((int)sw2, true);\
                floatx2 lo1 = __builtin_amdgcn_cvt_pk_f32_fp8((int)sw3, false);\
                floatx2 hi1 = __builtin_amdgcn_cvt_pk_f32_fp8((int)sw3, true);\
                d0 = fmaf(lo0.x, p0[0], d0); d1 = fmaf(lo1.x, p1[0], d1);    \
                d0 = fmaf(lo0.y, p0[1], d0); d1 = fmaf(lo1.y, p1[1], d1);    \
                d0 = fmaf(hi0.x, p0[2], d0); d1 = fmaf(hi1.x, p1[2], d1);    \
                d0 = fmaf(hi0.y, p0[3], d0); d1 = fmaf(hi1.y, p1[3], d1);    \
            }                                                                \
            float dot = d0 + d1;                                             \
            dot += __shfl_xor(dot, 16);                                      \
            dot += __shfl_xor(dot, 32);                                      \
            float x = sign * (dot + (BI));                                   \
            float sp = fmaxf(x, 0.0f) + __logf(1.0f + __expf(-fabsf(x)));    \
            bool live = (quad == 0) && (RECV != SENT);                       \
            loss += live ? sp : 0.0f;                                        \
        } while (0)

    int start = (wid * tg) >> 3;
    int end   = ((wid + 1) * tg) >> 3;

    const floatx4 zero4 = {0.0f, 0.0f, 0.0f, 0.0f};

    if (start < end) {
        // two disjoint stage sets, manual unroll x2, fetch distance 2 items
        unsigned recX, recY;
        uint4 SX, DX, SY, DY;
        uint4 wX0, wX1, wX2, wX3, wY0, wY1, wY2, wY3;
        float bX, bY;

        ISSUE(start,     recX, SX, DX, wX0, wX1, wX2, wX3, bX);
        ISSUE(start + 1, recY, SY, DY, wY0, wY1, wY2, wY3, bY);

        int n2 = (end - start + 1) >> 1;
        #pragma clang loop unroll(disable)
        for (int k = 0; k < n2; ++k) {
            int it = start + 2 * k;
            COMPUTE(recX, SX, DX, wX0, wX1, wX2, wX3, bX);
            ISSUE(it + 2, recX, SX, DX, wX0, wX1, wX2, wX3, bX);

            COMPUTE(recY, SY, DY, wY0, wY1, wY2, wY3, bY);
            ISSUE(it + 3, recY, SY, DY, wY0, wY1, wY2, wY3, bY);
        }
    }

    loss += __shfl_xor(loss, 1);
    loss += __shfl_xor(loss, 2);
    loss += __shfl_xor(loss, 4);
    loss += __shfl_xor(loss, 8);
    loss += __shfl_xor(loss, 16);
    loss += __shfl_xor(loss, 32);
    if (lane == 0) red[wid] = loss;
    __syncthreads();
    if (threadIdx.x == 0) {
        float t = red[0] + red[1] + red[2] + red[3]
                + red[4] + red[5] + red[6] + red[7];
        atomicAdd(out, t * (1.0f / (float)E_EDGES));
    }
}

extern "C" void kernel_launch(void* const* d_in, const int* in_sizes, int n_in,
                              void* d_out, int out_size, void* d_ws, size_t ws_size,
                              hipStream_t stream) {
    const float* assign = (const float*)d_in[0];
    const float* icl    = (const float*)d_in[1];
    const float* la     = (const float*)d_in[2];
    const float* ab     = (const float*)d_in[3];
    const int*   ei     = (const int*)d_in[4];
    const int*   et     = (const int*)d_in[5];
    const int*   nei    = (const int*)d_in[6];
    const int*   net    = (const int*)d_in[7];
    float* out = (float*)d_out;

    // workspace: Wp8 32KB (pad 64KB) | AS8 3.2MB
    char* basep = (char*)d_ws;
    unsigned char* Wp8 = (unsigned char*)basep;
    unsigned char* AS8 = (unsigned char*)(basep + 65536);

    prep_kernel<<<256, 256, 0, stream>>>(assign, icl, la, Wp8, AS8, out);
    edge_kernel<<<2 * NBLK, BT, 0, stream>>>(AS8, Wp8, ab, ei, et, nei, net, out);
}

// Round 22
// 128.568 us; speedup vs baseline: 1.0571x; 1.0571x over previous
//
#include <hip/hip_runtime.h>
#include <hip/hip_bf16.h>
#include <math.h>

#define E_EDGES 1000000
#define N_NODES 50000
#define N_C     64
#define N_REL   8
#define CHB     2048        // edges per block (best measured: R3/R10)
#define CAP     384         // per-rel LDS capacity (mean 256, sigma 15 -> 8.5 sigma)
#define NBLK    489         // ceil(1e6 / 2048)
#define BT      512         // 8 waves per block
#define SENT    0xFFFFFFFFu

typedef __attribute__((ext_vector_type(4))) float floatx4;
typedef __attribute__((ext_vector_type(2))) float floatx2;

// pack 4 fp32 -> 4 fp8 e4m3 (RNE); byte j = element j
static __device__ __forceinline__ unsigned pk4_fp8(float a, float b, float c, float d) {
    unsigned w = 0;
    w = __builtin_amdgcn_cvt_pk_fp8_f32(a, b, w, false);
    w = __builtin_amdgcn_cvt_pk_fp8_f32(c, d, w, true);
    return w;
}

static __device__ __forceinline__ long long pack64(unsigned lo, unsigned hi) {
    uint2 u; u.x = lo; u.y = hi;
    return __builtin_bit_cast(long long, u);
}

// kappa slot permutation (verified R11/R12): Wp8 byte (q*16 + c*8 + j) of row
// holds fp8(W[row][(2c+(j>>2))*16 + 4q + (j&3)]); AS8 row byte q*16+u holds
// elem (u>>2)*16 + 4q + (u&3). One b128 per lane serves both the MFMA B-op
// and the src dot.
__global__ __launch_bounds__(256) void prep_kernel(
    const float* __restrict__ assign,
    const float* __restrict__ icl,
    const float* __restrict__ la,
    unsigned char* __restrict__ Wp8,
    unsigned char* __restrict__ AS8,
    float* __restrict__ out)
{
    int tid = blockIdx.x * blockDim.x + threadIdx.x;
    int nth = gridDim.x * blockDim.x;
    if (tid == 0) out[0] = 0.0f;

    // Wp8: one thread per output dword (512 rows x 16 dwords)
    for (int idx = tid; idx < N_REL * N_C * 16; idx += nth) {
        int row = idx >> 4, dq = idx & 15;
        int q = dq >> 2, c = (dq >> 1) & 1, jh = dq & 1;
        int k0 = (2 * c + jh) * 16 + 4 * q;   // bytes b=0..3 -> k = k0 + b
        float wv[4];
        #pragma unroll
        for (int b = 0; b < 4; ++b) {
            int srci = (row << 6) + k0 + b;
            float w = 1.0f / (1.0f + __expf(-icl[srci]));
            float g = 1.0f / (1.0f + __expf(-la[srci])) * 1.2f - 0.1f;
            g = fminf(fmaxf(g, 0.0f), 1.0f);
            wv[b] = w * g;
        }
        ((unsigned*)Wp8)[idx] = pk4_fp8(wv[0], wv[1], wv[2], wv[3]);
    }

    // AS8: one thread per node row; dword[q*4 + mt] = elems [16mt+4q, +4)
    for (int n = tid; n < N_NODES; n += nth) {
        const float4* a4 = (const float4*)(assign + (size_t)n * N_C);
        unsigned w[16];
        #pragma unroll
        for (int i = 0; i < 16; ++i) {
            float4 v = a4[i];
            w[i] = pk4_fp8(v.x, v.y, v.z, v.w);   // w[i] = elems 4i..4i+3
        }
        uint4* as = (uint4*)(AS8 + (size_t)n * N_C);
        #pragma unroll
        for (int q = 0; q < 4; ++q) {
            uint4 o;
            o.x = w[0 * 4 + q];
            o.y = w[1 * 4 + q];
            o.z = w[2 * 4 + q];
            o.w = w[3 * 4 + q];
            as[q] = o;
        }
    }
}

// FINAL (measured 48.0us edge / 126.4us total, R13): flat (relation,group)
// worklist, BT=512, depth-1 S/D prefetch, spill-free at launch_bounds(512,5)
// (the 25MB spill WRITE_SIZE of bounds(512,8) was the one real pathology;
// fixing it was -4.6us). Session falsification sweep: occupancy x2 flat;
// compiler-held SWP collapsed in 4 structures (VGPR pinned 36-64); nt-loads
// and SALU scalarization flat; src-bucketing costs more than it saves
// (scatter 107us); W-in-LDS adds conflicts and cuts occupancy for zero
// benefit; inline-asm gathers with hand-counted vmcnt crash (regalloc
// cannot be made to respect in-flight asm destinations from HIP source).
// Edge kernel is pinned by the serial L2-gather chain at compiler-enforced
// pipeline depth 1: both compute pipes <35%, HBM 6% -- the practical floor
// of this per-edge-gather formulation in safe HIP.
__global__ __launch_bounds__(BT, 5) void edge_kernel(
    const unsigned char* __restrict__ AS8,
    const unsigned char* __restrict__ Wp8,
    const float* __restrict__ absent_bias,
    const int* __restrict__ ei, const int* __restrict__ et,
    const int* __restrict__ nei, const int* __restrict__ net,
    float* __restrict__ out)
{
    __shared__ unsigned list[N_REL * CAP];   // 12288 B
    __shared__ unsigned cnt[N_REL];
    __shared__ float red[8];
    if (threadIdx.x < N_REL) cnt[threadIdx.x] = 0u;
    __syncthreads();

    int blk = blockIdx.x;
    bool isneg = blk >= NBLK;
    int lb = isneg ? blk - NBLK : blk;
    const int* Es = isneg ? nei : ei;
    const int* Et = isneg ? net : et;
    float sign = isneg ? 1.0f : -1.0f;
    int base = lb * CHB;
    int elim = min(base + CHB, E_EDGES);

    // binning: batch all nt-loads up front (4-deep MLP), then atomics
    {
        int e0 = base + threadIdx.x;
        int sv[4], dv[4], rv[4];
        bool mv[4];
        #pragma unroll
        for (int k = 0; k < 4; ++k) {
            int e = e0 + k * BT;
            mv[k] = e < elim;
            int ec = mv[k] ? e : base;
            sv[k] = __builtin_nontemporal_load(&Es[ec]);
            dv[k] = __builtin_nontemporal_load(&Es[E_EDGES + ec]);
            rv[k] = __builtin_nontemporal_load(&Et[ec]);
        }
        #pragma unroll
        for (int k = 0; k < 4; ++k) {
            if (mv[k]) {
                unsigned rank = atomicAdd(&cnt[rv[k]], 1u);
                if (rank < CAP)
                    list[rv[k] * CAP + rank] = (unsigned)sv[k] | ((unsigned)dv[k] << 16);
            }
        }
    }
    __syncthreads();

    // sentinel-pad each relation's list up to a multiple of 16 entries
    if (threadIdx.x < N_REL * 16) {
        int r = threadIdx.x >> 4;
        int i = threadIdx.x & 15;
        int n = min((int)cnt[r], CAP);
        int padded = ((n + 15) >> 4) << 4;
        int slot = n + i;
        if (slot < padded) list[r * CAP + slot] = SENT;
    }
    __syncthreads();

    int lane = threadIdx.x & 63;
    int wid  = __builtin_amdgcn_readfirstlane(threadIdx.x >> 6);   // 0..7
    int n16  = lane & 15;
    int quad = lane >> 4;
    float loss = 0.0f;

    // group-offset table, scalar-resident (readfirstlane -> SGPR)
    int G0 = __builtin_amdgcn_readfirstlane((min((int)cnt[0], CAP) + 15) >> 4);
    int G1 = __builtin_amdgcn_readfirstlane((min((int)cnt[1], CAP) + 15) >> 4);
    int G2 = __builtin_amdgcn_readfirstlane((min((int)cnt[2], CAP) + 15) >> 4);
    int G3 = __builtin_amdgcn_readfirstlane((min((int)cnt[3], CAP) + 15) >> 4);
    int G4 = __builtin_amdgcn_readfirstlane((min((int)cnt[4], CAP) + 15) >> 4);
    int G5 = __builtin_amdgcn_readfirstlane((min((int)cnt[5], CAP) + 15) >> 4);
    int G6 = __builtin_amdgcn_readfirstlane((min((int)cnt[6], CAP) + 15) >> 4);
    int G7 = __builtin_amdgcn_readfirstlane((min((int)cnt[7], CAP) + 15) >> 4);
    int go1 = G0;
    int go2 = go1 + G1;
    int go3 = go2 + G2;
    int go4 = go3 + G3;
    int go5 = go4 + G4;
    int go6 = go5 + G5;
    int go7 = go6 + G6;
    int tg  = go7 + G7;

    // locate: item -> (relation r, group offset gof); all-scalar select chain
    #define LOCATE(ITEM, R, GOF)                                   \
        do {                                                       \
            R = 0; GOF = 0;                                        \
            if ((ITEM) >= go1) { R = 1; GOF = go1; }               \
            if ((ITEM) >= go2) { R = 2; GOF = go2; }               \
            if ((ITEM) >= go3) { R = 3; GOF = go3; }               \
            if ((ITEM) >= go4) { R = 4; GOF = go4; }               \
            if ((ITEM) >= go5) { R = 5; GOF = go5; }               \
            if ((ITEM) >= go6) { R = 6; GOF = go6; }               \
            if ((ITEM) >= go7) { R = 7; GOF = go7; }               \
        } while (0)

    // fetch rec + S/D gather for a flat item (R, GOF scalar)
    #define FETCH(ITEM, R, V, SREG, DREG)                                    \
        do {                                                                 \
            int gof_;                                                        \
            LOCATE(ITEM, R, gof_);                                           \
            unsigned rec_ = list[R * CAP + ((ITEM) - gof_) * 16 + n16];      \
            V = rec_ != SENT;                                                \
            unsigned sm_ = V ? (rec_ & 0xFFFFu) : 0u;                        \
            unsigned dm_ = V ? (rec_ >> 16) : 0u;                            \
            SREG = *(const uint4*)(AS8 + ((size_t)sm_ << 6) + quad * 16);    \
            DREG = *(const uint4*)(AS8 + ((size_t)dm_ << 6) + quad * 16);    \
        } while (0)

    int start = (wid * tg) >> 3;
    int end   = ((wid + 1) * tg) >> 3;

    int rC = 0;
    bool vC = false;
    uint4 SC = {0, 0, 0, 0}, DC = {0, 0, 0, 0};
    uint4 wfm[4];
    float bias = 0.0f;
    const floatx4 zero4 = {0.0f, 0.0f, 0.0f, 0.0f};

    if (start < end) {
        FETCH(start, rC, vC, SC, DC);
        #pragma unroll
        for (int mt = 0; mt < 4; ++mt)
            wfm[mt] = *(const uint4*)(Wp8 + ((rC * 64 + mt * 16 + n16) << 6) + quad * 16);
        bias = absent_bias[rC];
    }

    for (int it = start; it < end; ++it) {
        // prefetch next item (crosses relation boundaries)
        int rN = rC;
        bool vN = false;
        uint4 SN = {0, 0, 0, 0}, DN = {0, 0, 0, 0};
        if (it + 1 < end) {
            FETCH(it + 1, rN, vN, SN, DN);
        }

        // compute current item: 16 edges, W[rC] x D then dot with S
        long long bD0 = pack64(DC.x, DC.y);   // c=0 slots (first K=32)
        long long bD1 = pack64(DC.z, DC.w);   // c=1 slots
        unsigned sw[4] = {SC.x, SC.y, SC.z, SC.w};
        float d0 = 0.0f, d1 = 0.0f;
        #pragma unroll
        for (int gidx = 0; gidx < 2; ++gidx) {
            const int ma = 2 * gidx, mb = 2 * gidx + 1;
            floatx4 p0 = zero4, p1 = zero4;
            p0 = __builtin_amdgcn_mfma_f32_16x16x32_fp8_fp8(
                    pack64(wfm[ma].x, wfm[ma].y), bD0, p0, 0, 0, 0);
            p1 = __builtin_amdgcn_mfma_f32_16x16x32_fp8_fp8(
                    pack64(wfm[mb].x, wfm[mb].y), bD0, p1, 0, 0, 0);
            p0 = __builtin_amdgcn_mfma_f32_16x16x32_fp8_fp8(
                    pack64(wfm[ma].z, wfm[ma].w), bD1, p0, 0, 0, 0);
            p1 = __builtin_amdgcn_mfma_f32_16x16x32_fp8_fp8(
                    pack64(wfm[mb].z, wfm[mb].w), bD1, p1, 0, 0, 0);
            floatx2 lo0 = __builtin_amdgcn_cvt_pk_f32_fp8((int)sw[ma], false);
            floatx2 hi0 = __builtin_amdgcn_cvt_pk_f32_fp8((int)sw[ma], true);
            floatx2 lo1 = __builtin_amdgcn_cvt_pk_f32_fp8((int)sw[mb], false);
            floatx2 hi1 = __builtin_amdgcn_cvt_pk_f32_fp8((int)sw[mb], true);
            d0 = fmaf(lo0.x, p0[0], d0);
            d1 = fmaf(lo1.x, p1[0], d1);
            d0 = fmaf(lo0.y, p0[1], d0);
            d1 = fmaf(lo1.y, p1[1], d1);
            d0 = fmaf(hi0.x, p0[2], d0);
            d1 = fmaf(hi1.x, p1[2], d1);
            d0 = fmaf(hi0.y, p0[3], d0);
            d1 = fmaf(hi1.y, p1[3], d1);
        }
        float dot = d0 + d1;
        dot += __shfl_xor(dot, 16);
        dot += __shfl_xor(dot, 32);
        if (quad == 0 && vC) {
            float x = sign * (dot + bias);
            loss += fmaxf(x, 0.0f) + __logf(1.0f + __expf(-fabsf(x)));
        }

        // rotate stage; reload W only on relation change (scalar branch,
        // taken <= 7 times per wave with the sorted flat worklist)
        if (rN != rC) {
            #pragma unroll
            for (int mt = 0; mt < 4; ++mt)
                wfm[mt] = *(const uint4*)(Wp8 + ((rN * 64 + mt * 16 + n16) << 6) + quad * 16);
            bias = absent_bias[rN];
            rC = rN;
        }
        vC = vN; SC = SN; DC = DN;
    }

    loss += __shfl_xor(loss, 1);
    loss += __shfl_xor(loss, 2);
    loss += __shfl_xor(loss, 4);
    loss += __shfl_xor(loss, 8);
    loss += __shfl_xor(loss, 16);
    loss += __shfl_xor(loss, 32);
    if (lane == 0) red[wid] = loss;
    __syncthreads();
    if (threadIdx.x == 0) {
        float t = red[0] + red[1] + red[2] + red[3]
                + red[4] + red[5] + red[6] + red[7];
        atomicAdd(out, t * (1.0f / (float)E_EDGES));
    }
}

extern "C" void kernel_launch(void* const* d_in, const int* in_sizes, int n_in,
                              void* d_out, int out_size, void* d_ws, size_t ws_size,
                              hipStream_t stream) {
    const float* assign = (const float*)d_in[0];
    const float* icl    = (const float*)d_in[1];
    const float* la     = (const float*)d_in[2];
    const float* ab     = (const float*)d_in[3];
    const int*   ei     = (const int*)d_in[4];
    const int*   et     = (const int*)d_in[5];
    const int*   nei    = (const int*)d_in[6];
    const int*   net    = (const int*)d_in[7];
    float* out = (float*)d_out;

    // workspace: Wp8 32KB (pad 64KB) | AS8 3.2MB
    char* basep = (char*)d_ws;
    unsigned char* Wp8 = (unsigned char*)basep;
    unsigned char* AS8 = (unsigned char*)(basep + 65536);

    prep_kernel<<<256, 256, 0, stream>>>(assign, icl, la, Wp8, AS8, out);
    edge_kernel<<<2 * NBLK, BT, 0, stream>>>(AS8, Wp8, ab, ei, et, nei, net, out);
}